// Round 1
// baseline (38217.984 us; speedup 1.0000x reference)
//
#include <hip/hip_runtime.h>
#include <hip/hip_bf16.h>
#include <cstdint>
#include <cstddef>

#define T_STEPS 32768
#define DD 64
#define HH 128
#define GG 512   // 4*H

// d_out layout (float32, concatenated flat):
//   step       (T,11) at 0
//   experience (T,2)  at 360448
//   rsd        (T,1)  at 425984
//   s          (T,1)  at 458752
#define OFF_EXP 360448
#define OFF_RSD 425984
#define OFF_S   458752

__device__ __forceinline__ float sigm_f(float x) {
    return 1.0f / (1.0f + __expf(-x));
}
__device__ __forceinline__ float tanh_f(float x) {
    // stable both directions: x->+inf => 1, x->-inf => -1
    return 1.0f - 2.0f / (__expf(2.0f * x) + 1.0f);
}

// ---------------------------------------------------------------------------
// Kernel 1: P[r][j] = dot(X[t0+r,:], W_ih[j,:]) + b_ih[j] + b_hh[j]
// grid: nb blocks x 512 threads; each thread caches its W_ih row in registers.
// ---------------------------------------------------------------------------
__global__ __launch_bounds__(512) void pregate_kernel(
    const float* __restrict__ X, const float* __restrict__ W_ih,
    const float* __restrict__ b_ih, const float* __restrict__ b_hh,
    float* __restrict__ P, int t0, int nrows)
{
    __shared__ __align__(16) float xs[DD];
    const int j = threadIdx.x;

    float w[DD];
    const float4* wv = reinterpret_cast<const float4*>(W_ih + (size_t)j * DD);
#pragma unroll
    for (int k = 0; k < DD / 4; ++k) {
        float4 v = wv[k];
        w[4*k+0] = v.x; w[4*k+1] = v.y; w[4*k+2] = v.z; w[4*k+3] = v.w;
    }
    const float bias = b_ih[j] + b_hh[j];

    const int rpb = (nrows + gridDim.x - 1) / gridDim.x;
    const int r0  = blockIdx.x * rpb;
    const int r1  = (r0 + rpb < nrows) ? (r0 + rpb) : nrows;

    for (int r = r0; r < r1; ++r) {
        const int t = t0 + r;
        if (j < DD) xs[j] = X[(size_t)t * DD + j];
        __syncthreads();
        float acc = bias;
        const float4* xv = reinterpret_cast<const float4*>(xs);
#pragma unroll
        for (int k = 0; k < DD / 4; ++k) {
            float4 v = xv[k];
            acc += v.x*w[4*k+0] + v.y*w[4*k+1] + v.z*w[4*k+2] + v.w*w[4*k+3];
        }
        P[(size_t)r * GG + j] = acc;
        __syncthreads();
    }
}

// ---------------------------------------------------------------------------
// Heads: 15 outputs = dot(h, WH[o,:]) + bh[o]; 8 threads per output (j<120).
// ---------------------------------------------------------------------------
__device__ __forceinline__ void do_heads(int j, int gt,
                                         const float* __restrict__ h_lds,
                                         const float* __restrict__ wh,
                                         const float* __restrict__ bh,
                                         float* __restrict__ out)
{
    if (j >= 120) return;
    const int oi = j >> 3;   // 0..14
    const int l8 = j & 7;
    const float* hp = h_lds + l8 * 16;
    const float* wp = wh + oi * HH + l8 * 16;
    float s = 0.0f;
#pragma unroll
    for (int i = 0; i < 16; ++i) s += hp[i] * wp[i];
    s += __shfl_down(s, 4);
    s += __shfl_down(s, 2);
    s += __shfl_down(s, 1);
    if (l8 == 0) {
        s += bh[oi];
        if (oi < 11)       out[(size_t)gt * 11 + oi] = s;
        else if (oi < 13)  out[OFF_EXP + (size_t)gt * 2 + (oi - 11)] = s;
        else if (oi == 13) out[OFF_RSD + gt] = s;
        else               out[OFF_S   + gt] = s;
    }
}

// ---------------------------------------------------------------------------
// Kernel 2: sequential LSTM over C steps, single workgroup (512 thr = 8 waves).
// Thread j owns gate j: 128-FMA dot of h (LDS broadcast) with its W_hh row
// (registers). Threads 0..127 then do the cell update; heads fused.
// state (in ws): [0..127]=h, [128..255]=c, carried across chunks.
// ---------------------------------------------------------------------------
__global__ __launch_bounds__(512) void lstm_seq_kernel(
    const float* __restrict__ P, const float* __restrict__ W_hh,
    const float* __restrict__ W1, const float* __restrict__ b1,
    const float* __restrict__ W2, const float* __restrict__ b2,
    const float* __restrict__ W3, const float* __restrict__ b3,
    const float* __restrict__ W4, const float* __restrict__ b4,
    float* __restrict__ out, float* __restrict__ state,
    int t0, int C, int lastChunk)
{
    __shared__ __align__(16) float h_lds[HH];
    __shared__ float gate_lds[GG];
    __shared__ __align__(16) float wh[15 * HH];
    __shared__ float bh[15];

    const int j = threadIdx.x;

    // W_hh row j -> registers (128 VGPRs)
    float w[HH];
    const float4* wv = reinterpret_cast<const float4*>(W_hh + (size_t)j * HH);
#pragma unroll
    for (int k = 0; k < HH / 4; ++k) {
        float4 v = wv[k];
        w[4*k+0] = v.x; w[4*k+1] = v.y; w[4*k+2] = v.z; w[4*k+3] = v.w;
    }

    // head weights -> LDS (15 x 128)
    for (int i = j; i < 15 * HH; i += GG) {
        const int r = i >> 7;
        const int cidx = i & (HH - 1);
        float v;
        if (r < 11)      v = W1[r * HH + cidx];
        else if (r < 13) v = W2[(r - 11) * HH + cidx];
        else if (r == 13) v = W3[cidx];
        else             v = W4[cidx];
        wh[i] = v;
    }
    if (j < 15) {
        bh[j] = (j < 11) ? b1[j] : (j < 13) ? b2[j - 11] : (j == 13) ? b3[0] : b4[0];
    }

    float c = 0.0f;
    if (j < HH) {
        if (t0 == 0) {
            h_lds[j] = 0.0f;
        } else {
            h_lds[j] = state[j];
            c        = state[HH + j];
        }
    }
    __syncthreads();

    float pcur = P[j];
    float pn1  = (C > 1) ? P[GG + j] : 0.0f;

#pragma unroll 1
    for (int r = 0; r < C; ++r) {
        // prefetch P two steps ahead (hide HBM latency under the matvec)
        float pn2 = (r + 2 < C) ? P[(size_t)(r + 2) * GG + j] : 0.0f;

        // heads for the previous row (h_lds still holds h_{t0+r-1})
        const int gt = t0 + r - 1;
        if (gt >= 0) do_heads(j, gt, h_lds, wh, bh, out);

        // recurrent matvec: gate j = pcur + dot(h, W_hh[j,:])
        float a0 = pcur, a1 = 0.0f, a2 = 0.0f, a3 = 0.0f;
        const float4* h4 = reinterpret_cast<const float4*>(h_lds);
#pragma unroll
        for (int k = 0; k < HH / 4; ++k) {
            float4 v = h4[k];     // broadcast LDS read, conflict-free
            a0 += v.x * w[4*k+0];
            a1 += v.y * w[4*k+1];
            a2 += v.z * w[4*k+2];
            a3 += v.w * w[4*k+3];
        }
        const float gacc = (a0 + a1) + (a2 + a3);
        // quarters: 0=i (sig), 1=f (sig), 2=g (tanh), 3=o (sig)
        gate_lds[j] = ((j >> 7) == 2) ? tanh_f(gacc) : sigm_f(gacc);
        __syncthreads();

        if (j < HH) {
            const float ig = gate_lds[j];
            const float fg = gate_lds[HH + j];
            const float gg = gate_lds[2 * HH + j];
            const float og = gate_lds[3 * HH + j];
            c = fg * c + ig * gg;
            h_lds[j] = og * tanh_f(c);
        }
        __syncthreads();

        pcur = pn1;
        pn1  = pn2;
    }

    // heads for the last row of this chunk
    if (lastChunk) {
        do_heads(j, t0 + C - 1, h_lds, wh, bh, out);
    }
    // persist state for the next chunk (no consumer on last chunk; harmless)
    if (j < HH) {
        state[j]      = h_lds[j];
        state[HH + j] = c;
    }
}

// ---------------------------------------------------------------------------
extern "C" void kernel_launch(void* const* d_in, const int* in_sizes, int n_in,
                              void* d_out, int out_size, void* d_ws, size_t ws_size,
                              hipStream_t stream)
{
    const float* X    = (const float*)d_in[0];
    const float* W_ih = (const float*)d_in[1];
    const float* W_hh = (const float*)d_in[2];
    const float* b_ih = (const float*)d_in[3];
    const float* b_hh = (const float*)d_in[4];
    const float* W1   = (const float*)d_in[5];
    const float* b1   = (const float*)d_in[6];
    const float* W2   = (const float*)d_in[7];
    const float* b2   = (const float*)d_in[8];
    const float* W3   = (const float*)d_in[9];
    const float* b3   = (const float*)d_in[10];
    const float* W4   = (const float*)d_in[11];
    const float* b4   = (const float*)d_in[12];

    float* out   = (float*)d_out;
    float* state = (float*)d_ws;          // 256 floats (1 KB): h then c
    float* P     = state + 256;

    // chunk the sequence if ws can't hold all T*512 pregate floats
    size_t avail_rows = (ws_size > 1024) ? (ws_size - 1024) / (GG * sizeof(float)) : 0;
    int C = (avail_rows >= (size_t)T_STEPS) ? T_STEPS : (int)avail_rows;
    if (C < 1) C = 1;

    for (int t0 = 0; t0 < T_STEPS; t0 += C) {
        const int Cc = (C < T_STEPS - t0) ? C : (T_STEPS - t0);
        const int nb = (Cc < 512) ? Cc : 512;
        pregate_kernel<<<nb, 512, 0, stream>>>(X, W_ih, b_ih, b_hh, P, t0, Cc);
        lstm_seq_kernel<<<1, 512, 0, stream>>>(P, W_hh, W1, b1, W2, b2, W3, b3, W4, b4,
                                               out, state, t0, Cc,
                                               (t0 + Cc >= T_STEPS) ? 1 : 0);
    }
}